// Round 26
// baseline (677.202 us; speedup 1.0000x reference)
//
#include <hip/hip_runtime.h>
#include <hip/hip_bf16.h>
#include <hip/hip_fp8.h>
#include <math.h>

#define IGNORE_INDEX (-100)

static constexpr int Dc = 1024, Vc = 128000;
static constexpr int Mrows = 2048;        // B*S
static constexpr int Kdim = 1024;
static constexpr int BK = 64;             // fp8: 64 elems = 64 B LDS rows
static constexpr int NT = Kdim / BK;      // 16 K-tiles
static constexpr int NCHUNK = Vc / 64;    // 2000 partial chunks per row

typedef float f32x4_t __attribute__((ext_vector_type(4)));

// ------- cast fp32 -> fp8 e4m3, PRE-SWIZZLED for 64B LDS rows ---------------
// (R25-verified: SQ_LDS_BANK_CONFLICT = 0, absmax 0)
// Within every 64B k-group of a row, 8B slot s stored at s ^ ((row>>1)&7).
__global__ void cast_f32_fp8_swz(const float* __restrict__ in, uchar* __restrict__ out,
                                 size_t n8) {
  size_t i = (size_t)blockIdx.x * blockDim.x + threadIdx.x;
  size_t stride = (size_t)gridDim.x * blockDim.x;
  for (; i < n8; i += stride) {
    size_t byte0 = i * 8;                 // logical fp8 byte index (slot-aligned)
    size_t row = byte0 >> 10;             // 1024 B per K-row
    int s = (int)(byte0 >> 3) & 7;        // 8B slot within 64B group
    int sw = s ^ ((int)(row >> 1) & 7);
    size_t obyte = (byte0 & ~(size_t)63) | ((size_t)sw << 3);
    float4 v0 = *reinterpret_cast<const float4*>(in + byte0);
    float4 v1 = *reinterpret_cast<const float4*>(in + byte0 + 4);
    union { uchar b[8]; unsigned long long u; } p;
    p.b[0] = __hip_fp8_e4m3(v0.x).__x; p.b[1] = __hip_fp8_e4m3(v0.y).__x;
    p.b[2] = __hip_fp8_e4m3(v0.z).__x; p.b[3] = __hip_fp8_e4m3(v0.w).__x;
    p.b[4] = __hip_fp8_e4m3(v1.x).__x; p.b[5] = __hip_fp8_e4m3(v1.y).__x;
    p.b[6] = __hip_fp8_e4m3(v1.z).__x; p.b[7] = __hip_fp8_e4m3(v1.w).__x;
    *reinterpret_cast<unsigned long long*>(out + obyte) = p.u;
  }
}

// ---------------- target logits: fp32 dot(hidden[r], weight[t[r]]) — exact ----
__global__ void tgt_kernel(const float* __restrict__ hidden, const float* __restrict__ weight,
                           const int* __restrict__ targets, float* __restrict__ tgt) {
  int row = blockIdx.x * 4 + (threadIdx.x >> 6);
  int lane = threadIdx.x & 63;
  if (row >= Mrows) return;
  int t = targets[row];
  float sum = 0.f;
  if (t != IGNORE_INDEX) {
    const float* h = hidden + (size_t)row * Kdim;
    const float* wv = weight + (size_t)t * Kdim;
    for (int k = lane * 4; k < Kdim; k += 64 * 4) {
      float4 a = *reinterpret_cast<const float4*>(h + k);
      float4 b = *reinterpret_cast<const float4*>(wv + k);
      sum += a.x * b.x + a.y * b.y + a.z * b.z + a.w * b.w;
    }
  }
  #pragma unroll
  for (int d = 1; d < 64; d <<= 1) sum += __shfl_xor(sum, d);
  if (lane == 0) tgt[row] = sum;
}

// -- 128x512 8-wave ring-3 FP8 GEMM (wave 64x128) + fused partial LSE --------
// R25 cycle model: kernel is LDS-BYTES-bound (256 b64 reads ~1540 cyc vs MFMA
// 621 cyc per CU-tile). Fix = more reuse per wave: wave 64x128 (acc 128 AGPR,
// a[4]+b[8] operands) -> 24 reads per 64 MFMA (-25% LDS bytes/MFMA). Block
// 128x512, LDS ring-3 x 40KB = 120KB -> 1 block/CU (trade: cross-block
// overlap, +6% in R13). (512,2) caps 256 regs -> no spill (plain-fp8 MFMA
// allocated cleanly in R16-R25; the R20-23 spills were MX codegen only).
// Swizzle/read formulas identical to R25 (0-conflict-verified); counted
// vmcnt(5) = 5 uniform loads/STAGE (R8 rule upheld).
#define MFMA_FP8(A, B, C) __builtin_amdgcn_mfma_f32_16x16x32_fp8_fp8((A), (B), (C), 0, 0, 0)
#define GLDS(g, l) __builtin_amdgcn_global_load_lds( \
    (const __attribute__((address_space(1))) void*)(g), \
    (__attribute__((address_space(3))) void*)(l), 16, 0, 0)

__global__ __launch_bounds__(512, 2) void gemm_lse_fp8(const uchar* __restrict__ A8,
                                                       const uchar* __restrict__ B8,
                                                       float2* __restrict__ part) {
  __shared__ uchar lds[3][40960];      // [ring][A(128x64B)=8KB | B(512x64B)=32KB]
  const int tid = threadIdx.x;
  const int wid = tid >> 6, lane = tid & 63;
  const int wr = wid >> 2, wc = wid & 3;        // 2M x 4N wave grid, wave = 64x128 out
  const int l15 = lane & 15, l16 = lane >> 4;
  const int bid = blockIdx.x;
  const int mb = bid & 15;             // 16 M-blocks share one B panel
  const int nb = bid >> 4;             // 0..249 (V/512)

  // staging sources (16B-linear; data pre-swizzled by cast kernel).
  const uchar* gA = A8 + (size_t)(mb * 128) * 1024;
  const uchar* gB = B8 + (size_t)(nb * 512) * 1024;
  const uchar* sgA = gA + (size_t)(tid >> 2) * 1024 + (tid & 3) * 16;
  const uchar* sgB[4];
  #pragma unroll
  for (int j = 0; j < 4; ++j) {
    int c = j * 512 + tid;
    sgB[j] = gB + (size_t)(c >> 2) * 1024 + (c & 3) * 16;
  }

  // read-side swizzled offsets (per k-half h): slot = 4h + l16 ->
  // phys = slot ^ ((l15>>1)&7), byte off = phys*8.
  const int fsw = (l15 >> 1) & 7;
  const int koff0 = ((l16 ^ fsw) << 3);
  const int koff1 = (((4 | l16) ^ fsw) << 3);
  const int aBase = (wr * 64 + l15) * 64;    // + mi*1024 + koff_h
  const int bBase = (wc * 128 + l15) * 64;   // + ni*1024 + koff_h (B region +8192)

  f32x4_t acc[4][8];
  #pragma unroll
  for (int i = 0; i < 4; ++i)
    #pragma unroll
    for (int j = 0; j < 8; ++j)
      acc[i][j] = (f32x4_t){0.f, 0.f, 0.f, 0.f};

  #define STAGE(bufp, k0) do { \
    GLDS(sgA + (k0), (bufp) + tid * 16); \
    _Pragma("unroll") \
    for (int j = 0; j < 4; ++j) \
      GLDS(sgB[j] + (k0), (bufp) + 8192 + (j * 512 + tid) * 16); \
  } while (0)

  // prologue: tiles 0,1 staged; vmcnt(5) -> tile0's 5 loads retired
  STAGE(lds[0], 0);
  STAGE(lds[1], BK);
  asm volatile("s_waitcnt vmcnt(5)" ::: "memory");
  __builtin_amdgcn_s_barrier();

  int cur = 0;
  for (int t = 0; t < NT; ++t) {
    if (t + 2 < NT) {
      int stg = cur + 2; if (stg >= 3) stg -= 3;
      STAGE(lds[stg], (t + 2) * BK);
    }
    const uchar* Ar = lds[cur];
    const uchar* Br = lds[cur] + 8192;
    #pragma unroll
    for (int h = 0; h < 2; ++h) {
      const int koff = h ? koff1 : koff0;
      long a[4], b[8];
      #pragma unroll
      for (int mi = 0; mi < 4; ++mi)
        a[mi] = *reinterpret_cast<const long*>(Ar + aBase + mi * 1024 + koff);
      #pragma unroll
      for (int ni = 0; ni < 8; ++ni)
        b[ni] = *reinterpret_cast<const long*>(Br + bBase + ni * 1024 + koff);
      __builtin_amdgcn_s_setprio(1);
      #pragma unroll
      for (int mi = 0; mi < 4; ++mi)
        #pragma unroll
        for (int ni = 0; ni < 8; ++ni)
          acc[mi][ni] = MFMA_FP8(a[mi], b[ni], acc[mi][ni]);
      __builtin_amdgcn_s_setprio(0);
    }
    if (t + 1 < NT) {
      if (t + 2 < NT) asm volatile("s_waitcnt vmcnt(5)" ::: "memory");
      else            asm volatile("s_waitcnt vmcnt(0)" ::: "memory");
      __builtin_amdgcn_s_barrier();
    }
    cur = cur + 1; if (cur >= 3) cur = 0;
  }
  #undef STAGE

  // fused partial-LSE epilogue. acc[mi][ni][j]: row = wr*64+mi*16+l16*4+j,
  // col = wc*128 + ni*16 + l15 (m89 C/D layout). Two 64-col chunks per wave.
  #pragma unroll
  for (int mi = 0; mi < 4; ++mi) {
    #pragma unroll
    for (int j = 0; j < 4; ++j) {
      int grow = mb * 128 + wr * 64 + mi * 16 + l16 * 4 + j;
      #pragma unroll
      for (int h2 = 0; h2 < 2; ++h2) {
        float v0 = acc[mi][h2 * 4 + 0][j], v1 = acc[mi][h2 * 4 + 1][j];
        float v2 = acc[mi][h2 * 4 + 2][j], v3 = acc[mi][h2 * 4 + 3][j];
        float mloc = fmaxf(fmaxf(v0, v1), fmaxf(v2, v3));
        #pragma unroll
        for (int d = 1; d < 16; d <<= 1) mloc = fmaxf(mloc, __shfl_xor(mloc, d));
        float sloc = __expf(v0 - mloc) + __expf(v1 - mloc) +
                     __expf(v2 - mloc) + __expf(v3 - mloc);
        #pragma unroll
        for (int d = 1; d < 16; d <<= 1) sloc += __shfl_xor(sloc, d);
        if (l15 == 0) {
          int chunk = nb * 8 + wc * 2 + h2;
          part[(size_t)grow * NCHUNK + chunk] = make_float2(mloc, sloc);
        }
      }
    }
  }
}

// ---------------- per-row merge of partials -> nll[row] ----------------
__device__ __forceinline__ void merge_ms(float& m, float& s, float m2, float s2) {
  if (m2 > m) { s = s * __expf(m - m2) + s2; m = m2; }
  else        { s += s2 * __expf(m2 - m); }
}

__global__ void lse_reduce(const float2* __restrict__ part, const float* __restrict__ tgt,
                           const int* __restrict__ targets, float* __restrict__ nll) {
  int row = blockIdx.x;
  const float2* p = part + (size_t)row * NCHUNK;
  float m = -INFINITY, s = 0.f;
  for (int c = threadIdx.x; c < NCHUNK; c += blockDim.x) {
    float2 v = p[c];
    merge_ms(m, s, v.x, v.y);
  }
  #pragma unroll
  for (int d = 1; d < 64; d <<= 1) {
    float m2 = __shfl_xor(m, d), s2 = __shfl_xor(s, d);
    merge_ms(m, s, m2, s2);
  }
  __shared__ float sm[4], ss[4];
  int wid = threadIdx.x >> 6, lane = threadIdx.x & 63;
  if (lane == 0) { sm[wid] = m; ss[wid] = s; }
  __syncthreads();
  if (threadIdx.x == 0) {
    #pragma unroll
    for (int w2 = 1; w2 < 4; ++w2) merge_ms(m, s, sm[w2], ss[w2]);
    int t = targets[row];
    float out = 0.f;
    if (t != IGNORE_INDEX) out = m + logf(s) - tgt[row];
    nll[row] = out;
  }
}

// ---------------- final scalar: sum(nll)/count ----------------
__global__ void final_kernel(const float* __restrict__ nll, const int* __restrict__ targets,
                             float* __restrict__ out) {
  float sum = 0.f, cnt = 0.f;
  for (int i = threadIdx.x; i < Mrows; i += 64) {
    sum += nll[i];
    cnt += (targets[i] != IGNORE_INDEX) ? 1.f : 0.f;
  }
  #pragma unroll
  for (int d = 1; d < 64; d <<= 1) {
    sum += __shfl_xor(sum, d);
    cnt += __shfl_xor(cnt, d);
  }
  if (threadIdx.x == 0)
    out[0] = (cnt == 0.f) ? sum : sum / fmaxf(cnt, 1.f);
}

extern "C" void kernel_launch(void* const* d_in, const int* in_sizes, int n_in,
                              void* d_out, int out_size, void* d_ws, size_t ws_size,
                              hipStream_t stream) {
  const float* hidden = (const float*)d_in[0];   // [2,1024,1024] f32
  const float* weight = (const float*)d_in[1];   // [128000,1024] f32
  const int* targets  = (const int*)d_in[2];     // [2,1024] i32
  float* out = (float*)d_out;

  char* ws = (char*)d_ws;
  size_t off = 0;
  uchar* w8 = (uchar*)(ws + off); off += (size_t)Vc * Dc;                  // 128 MB
  uchar* h8 = (uchar*)(ws + off); off += (size_t)Mrows * Dc;               // 2 MB
  float2* part = (float2*)(ws + off); off += (size_t)Mrows * NCHUNK * sizeof(float2); // 32 MB
  float* tgt = (float*)(ws + off); off += Mrows * sizeof(float);
  float* nll = (float*)(ws + off); off += Mrows * sizeof(float);
  (void)ws_size; (void)in_sizes; (void)n_in; (void)out_size;

  cast_f32_fp8_swz<<<2048, 256, 0, stream>>>(weight, w8, (size_t)Vc * Dc / 8);
  cast_f32_fp8_swz<<<256, 256, 0, stream>>>(hidden, h8, (size_t)Mrows * Dc / 8);
  tgt_kernel<<<Mrows / 4, 256, 0, stream>>>(hidden, weight, targets, tgt);

  gemm_lse_fp8<<<4000, 512, 0, stream>>>(h8, w8, part);  // mb=bid&15, nb=bid>>4

  lse_reduce<<<Mrows, 256, 0, stream>>>(part, tgt, targets, nll);
  final_kernel<<<1, 64, 0, stream>>>(nll, targets, out);
}

// Round 27
// 521.589 us; speedup vs baseline: 1.2983x; 1.2983x over previous
//
#include <hip/hip_runtime.h>
#include <hip/hip_bf16.h>
#include <hip/hip_fp8.h>
#include <math.h>

#define IGNORE_INDEX (-100)

static constexpr int Dc = 1024, Vc = 128000;
static constexpr int Mrows = 2048;        // B*S
static constexpr int Kdim = 1024;
static constexpr int BK = 64;             // fp8: 64 elems = 64 B LDS rows
static constexpr int NT = Kdim / BK;      // 16 K-tiles
static constexpr int NCHUNK = Vc / 64;    // 2000 partial chunks per row

typedef float f32x4_t __attribute__((ext_vector_type(4)));

// ------- cast fp32 -> fp8 e4m3, PRE-SWIZZLED for 64B LDS rows ---------------
// (R25-verified: SQ_LDS_BANK_CONFLICT = 0, absmax 0)
// Within every 64B k-group of a row, 8B slot s stored at s ^ ((row>>1)&7).
// Bank check (ds_read_b64, 16-lane HW group, l15=2q+r):
// addr/8 mod 16 = 8r + ((4h+l16)^q) -> bijective -> all 32 banks, conflict-free.
__global__ void cast_f32_fp8_swz(const float* __restrict__ in, uchar* __restrict__ out,
                                 size_t n8) {
  size_t i = (size_t)blockIdx.x * blockDim.x + threadIdx.x;
  size_t stride = (size_t)gridDim.x * blockDim.x;
  for (; i < n8; i += stride) {
    size_t byte0 = i * 8;                 // logical fp8 byte index (slot-aligned)
    size_t row = byte0 >> 10;             // 1024 B per K-row
    int s = (int)(byte0 >> 3) & 7;        // 8B slot within 64B group
    int sw = s ^ ((int)(row >> 1) & 7);
    size_t obyte = (byte0 & ~(size_t)63) | ((size_t)sw << 3);
    float4 v0 = *reinterpret_cast<const float4*>(in + byte0);
    float4 v1 = *reinterpret_cast<const float4*>(in + byte0 + 4);
    union { uchar b[8]; unsigned long long u; } p;
    p.b[0] = __hip_fp8_e4m3(v0.x).__x; p.b[1] = __hip_fp8_e4m3(v0.y).__x;
    p.b[2] = __hip_fp8_e4m3(v0.z).__x; p.b[3] = __hip_fp8_e4m3(v0.w).__x;
    p.b[4] = __hip_fp8_e4m3(v1.x).__x; p.b[5] = __hip_fp8_e4m3(v1.y).__x;
    p.b[6] = __hip_fp8_e4m3(v1.z).__x; p.b[7] = __hip_fp8_e4m3(v1.w).__x;
    *reinterpret_cast<unsigned long long*>(out + obyte) = p.u;
  }
}

// ---------------- target logits: fp32 dot(hidden[r], weight[t[r]]) — exact ----
__global__ void tgt_kernel(const float* __restrict__ hidden, const float* __restrict__ weight,
                           const int* __restrict__ targets, float* __restrict__ tgt) {
  int row = blockIdx.x * 4 + (threadIdx.x >> 6);
  int lane = threadIdx.x & 63;
  if (row >= Mrows) return;
  int t = targets[row];
  float sum = 0.f;
  if (t != IGNORE_INDEX) {
    const float* h = hidden + (size_t)row * Kdim;
    const float* wv = weight + (size_t)t * Kdim;
    for (int k = lane * 4; k < Kdim; k += 64 * 4) {
      float4 a = *reinterpret_cast<const float4*>(h + k);
      float4 b = *reinterpret_cast<const float4*>(wv + k);
      sum += a.x * b.x + a.y * b.y + a.z * b.z + a.w * b.w;
    }
  }
  #pragma unroll
  for (int d = 1; d < 64; d <<= 1) sum += __shfl_xor(sum, d);
  if (lane == 0) tgt[row] = sum;
}

// -- 128x256 8-wave 2-BLOCK/CU ring-3 FP8 GEMM (BK=64) + fused partial LSE ---
// R25-VERIFIED BEST (gemm 411us, 1307 TF = 64% of fp8 ceiling, MfmaUtil 59%,
// 0 conflicts). R26's wave-64x128 variant regressed (-29%): 1 block/CU lost
// cross-block overlap. This is the byte-identical R25 kernel.
#define MFMA_FP8(A, B, C) __builtin_amdgcn_mfma_f32_16x16x32_fp8_fp8((A), (B), (C), 0, 0, 0)
#define GLDS(g, l) __builtin_amdgcn_global_load_lds( \
    (const __attribute__((address_space(1))) void*)(g), \
    (__attribute__((address_space(3))) void*)(l), 16, 0, 0)

__global__ __launch_bounds__(512, 4) void gemm_lse_fp8(const uchar* __restrict__ A8,
                                                       const uchar* __restrict__ B8,
                                                       float2* __restrict__ part) {
  __shared__ uchar lds[3][24576];      // [ring][A(128x64B)=8KB | B(256x64B)=16KB]
  const int tid = threadIdx.x;
  const int wid = tid >> 6, lane = tid & 63;
  const int wr = wid >> 2, wc = wid & 3;        // 2M x 4N wave grid, wave = 64x64 out
  const int l15 = lane & 15, l16 = lane >> 4;
  const int bid = blockIdx.x;
  const int mb = bid & 15;             // 16 M-blocks share one B panel
  const int nb = bid >> 4;             // 0..499

  // staging sources (16B-linear; data pre-swizzled by cast kernel).
  const uchar* gA = A8 + (size_t)(mb * 128) * 1024;
  const uchar* gB = B8 + (size_t)(nb * 256) * 1024;
  const uchar* sgA  = gA + (size_t)(tid >> 2) * 1024 + (tid & 3) * 16;
  const uchar* sgB0 = gB + (size_t)(tid >> 2) * 1024 + (tid & 3) * 16;
  const uchar* sgB1 = gB + (size_t)((tid + 512) >> 2) * 1024 + (tid & 3) * 16;

  // read-side swizzled offsets (per k-half h): slot = 4h + l16 ->
  // phys = slot ^ ((l15>>1)&7), byte off = phys*8.
  const int fsw = (l15 >> 1) & 7;
  const int koff0 = ((l16 ^ fsw) << 3);
  const int koff1 = (((4 | l16) ^ fsw) << 3);
  const int aBase = (wr * 64 + l15) * 64;   // + mi*1024 + koff_h
  const int bBase = (wc * 64 + l15) * 64;   // + ni*1024 + koff_h (B region +8192)

  f32x4_t acc[4][4];
  #pragma unroll
  for (int i = 0; i < 4; ++i)
    #pragma unroll
    for (int j = 0; j < 4; ++j)
      acc[i][j] = (f32x4_t){0.f, 0.f, 0.f, 0.f};

  #define STAGE(bufp, k0) do { \
    GLDS(sgA + (k0), (bufp) + tid * 16); \
    GLDS(sgB0 + (k0), (bufp) + 8192 + tid * 16); \
    GLDS(sgB1 + (k0), (bufp) + 8192 + (tid + 512) * 16); \
  } while (0)

  // prologue: tiles 0,1 staged; vmcnt(3) -> tile0's 3 loads retired
  STAGE(lds[0], 0);
  STAGE(lds[1], BK);
  asm volatile("s_waitcnt vmcnt(3)" ::: "memory");
  __builtin_amdgcn_s_barrier();

  int cur = 0;
  for (int t = 0; t < NT; ++t) {
    if (t + 2 < NT) {
      int stg = cur + 2; if (stg >= 3) stg -= 3;
      STAGE(lds[stg], (t + 2) * BK);
    }
    const uchar* Ar = lds[cur];
    const uchar* Br = lds[cur] + 8192;
    #pragma unroll
    for (int h = 0; h < 2; ++h) {
      const int koff = h ? koff1 : koff0;
      long a[4], b[4];
      #pragma unroll
      for (int mi = 0; mi < 4; ++mi)
        a[mi] = *reinterpret_cast<const long*>(Ar + aBase + mi * 1024 + koff);
      #pragma unroll
      for (int ni = 0; ni < 4; ++ni)
        b[ni] = *reinterpret_cast<const long*>(Br + bBase + ni * 1024 + koff);
      __builtin_amdgcn_s_setprio(1);
      #pragma unroll
      for (int mi = 0; mi < 4; ++mi)
        #pragma unroll
        for (int ni = 0; ni < 4; ++ni)
          acc[mi][ni] = MFMA_FP8(a[mi], b[ni], acc[mi][ni]);
      __builtin_amdgcn_s_setprio(0);
    }
    if (t + 1 < NT) {
      if (t + 2 < NT) asm volatile("s_waitcnt vmcnt(3)" ::: "memory");
      else            asm volatile("s_waitcnt vmcnt(0)" ::: "memory");
      __builtin_amdgcn_s_barrier();
    }
    cur = cur + 1; if (cur >= 3) cur = 0;
  }
  #undef STAGE

  // fused partial-LSE epilogue. acc[mi][ni][j]: row = wr*64+mi*16+l16*4+j,
  // col = wc*64+ni*16+l15 (m89 C/D layout; dtype-independent m121-128)
  const int chunk = nb * 4 + wc;
  #pragma unroll
  for (int mi = 0; mi < 4; ++mi) {
    #pragma unroll
    for (int j = 0; j < 4; ++j) {
      float v0 = acc[mi][0][j], v1 = acc[mi][1][j], v2 = acc[mi][2][j], v3 = acc[mi][3][j];
      float mloc = fmaxf(fmaxf(v0, v1), fmaxf(v2, v3));
      #pragma unroll
      for (int d = 1; d < 16; d <<= 1) mloc = fmaxf(mloc, __shfl_xor(mloc, d));
      float sloc = __expf(v0 - mloc) + __expf(v1 - mloc) +
                   __expf(v2 - mloc) + __expf(v3 - mloc);
      #pragma unroll
      for (int d = 1; d < 16; d <<= 1) sloc += __shfl_xor(sloc, d);
      if (l15 == 0) {
        int grow = mb * 128 + wr * 64 + mi * 16 + l16 * 4 + j;
        part[(size_t)grow * NCHUNK + chunk] = make_float2(mloc, sloc);
      }
    }
  }
}

// ---------------- per-row merge of partials -> nll[row] ----------------
__device__ __forceinline__ void merge_ms(float& m, float& s, float m2, float s2) {
  if (m2 > m) { s = s * __expf(m - m2) + s2; m = m2; }
  else        { s += s2 * __expf(m2 - m); }
}

__global__ void lse_reduce(const float2* __restrict__ part, const float* __restrict__ tgt,
                           const int* __restrict__ targets, float* __restrict__ nll) {
  int row = blockIdx.x;
  const float2* p = part + (size_t)row * NCHUNK;
  float m = -INFINITY, s = 0.f;
  for (int c = threadIdx.x; c < NCHUNK; c += blockDim.x) {
    float2 v = p[c];
    merge_ms(m, s, v.x, v.y);
  }
  #pragma unroll
  for (int d = 1; d < 64; d <<= 1) {
    float m2 = __shfl_xor(m, d), s2 = __shfl_xor(s, d);
    merge_ms(m, s, m2, s2);
  }
  __shared__ float sm[4], ss[4];
  int wid = threadIdx.x >> 6, lane = threadIdx.x & 63;
  if (lane == 0) { sm[wid] = m; ss[wid] = s; }
  __syncthreads();
  if (threadIdx.x == 0) {
    #pragma unroll
    for (int w2 = 1; w2 < 4; ++w2) merge_ms(m, s, sm[w2], ss[w2]);
    int t = targets[row];
    float out = 0.f;
    if (t != IGNORE_INDEX) out = m + logf(s) - tgt[row];
    nll[row] = out;
  }
}

// ---------------- final scalar: sum(nll)/count ----------------
__global__ void final_kernel(const float* __restrict__ nll, const int* __restrict__ targets,
                             float* __restrict__ out) {
  float sum = 0.f, cnt = 0.f;
  for (int i = threadIdx.x; i < Mrows; i += 64) {
    sum += nll[i];
    cnt += (targets[i] != IGNORE_INDEX) ? 1.f : 0.f;
  }
  #pragma unroll
  for (int d = 1; d < 64; d <<= 1) {
    sum += __shfl_xor(sum, d);
    cnt += __shfl_xor(cnt, d);
  }
  if (threadIdx.x == 0)
    out[0] = (cnt == 0.f) ? sum : sum / fmaxf(cnt, 1.f);
}

extern "C" void kernel_launch(void* const* d_in, const int* in_sizes, int n_in,
                              void* d_out, int out_size, void* d_ws, size_t ws_size,
                              hipStream_t stream) {
  const float* hidden = (const float*)d_in[0];   // [2,1024,1024] f32
  const float* weight = (const float*)d_in[1];   // [128000,1024] f32
  const int* targets  = (const int*)d_in[2];     // [2,1024] i32
  float* out = (float*)d_out;

  char* ws = (char*)d_ws;
  size_t off = 0;
  uchar* w8 = (uchar*)(ws + off); off += (size_t)Vc * Dc;                  // 128 MB
  uchar* h8 = (uchar*)(ws + off); off += (size_t)Mrows * Dc;               // 2 MB
  float2* part = (float2*)(ws + off); off += (size_t)Mrows * NCHUNK * sizeof(float2); // 32 MB
  float* tgt = (float*)(ws + off); off += Mrows * sizeof(float);
  float* nll = (float*)(ws + off); off += Mrows * sizeof(float);
  (void)ws_size; (void)in_sizes; (void)n_in; (void)out_size;

  cast_f32_fp8_swz<<<2048, 256, 0, stream>>>(weight, w8, (size_t)Vc * Dc / 8);
  cast_f32_fp8_swz<<<256, 256, 0, stream>>>(hidden, h8, (size_t)Mrows * Dc / 8);
  tgt_kernel<<<Mrows / 4, 256, 0, stream>>>(hidden, weight, targets, tgt);

  gemm_lse_fp8<<<8000, 512, 0, stream>>>(h8, w8, part);  // mb=bid&15, nb=bid>>4

  lse_reduce<<<Mrows, 256, 0, stream>>>(part, tgt, targets, nll);
  final_kernel<<<1, 64, 0, stream>>>(nll, targets, out);
}